// Round 4
// baseline (462.447 us; speedup 1.0000x reference)
//
#include <hip/hip_runtime.h>

constexpr int NX = 192, NY = 192, NZ = 192, NB = 2;
constexpr int ZPT  = 4;           // z outputs per thread
constexpr int TZ   = NZ / ZPT;    // 48
constexpr int BY   = 4;           // y rows per block
constexpr int XSEG = 8;           // x outputs per thread
constexpr int BLOCK_THREADS = TZ * BY;   // 192 = 3 waves
constexpr int PLANE = NY * NZ;
constexpr int NXB = NX / XSEG;    // 24
constexpr int NYB = NY / BY;      // 48
constexpr int NBLK = NYB * NXB * NB;     // 2304

struct Raw { float t[3][6]; float p[3][6]; };

template<bool SAFE>
__device__ __forceinline__ void loadPlane(const float* __restrict__ pred,
                                          const float* __restrict__ label,
                                          int xx, const int rowoff[3],
                                          int dm, int de, Raw& R)
{
    const int xcl  = SAFE ? xx : min(max(xx, 0), NX - 1);
    const int xoff = xcl * PLANE;
    #pragma unroll
    for (int r = 0; r < 3; ++r) {
        const int off = xoff + rowoff[r];
        const float4 t4 = *reinterpret_cast<const float4*>(label + off);
        const float4 p4 = *reinterpret_cast<const float4*>(pred + off);
        R.t[r][0] = label[off - dm];  R.p[r][0] = pred[off - dm];
        R.t[r][1] = t4.x; R.t[r][2] = t4.y; R.t[r][3] = t4.z; R.t[r][4] = t4.w;
        R.p[r][1] = p4.x; R.p[r][2] = p4.y; R.p[r][3] = p4.z; R.p[r][4] = p4.w;
        R.t[r][5] = label[off + de];  R.p[r][5] = pred[off + de];
    }
}

template<bool SAFE>
__device__ __forceinline__ void foldPlane(const Raw& R, int xx,
                                          const float wy[3], float wzm, float wze,
                                          float W[5][ZPT])
{
    float S[5][6];
    #pragma unroll
    for (int r = 0; r < 3; ++r) {
        float wr = 1.f, wm = 1.f, we = 1.f;
        if (!SAFE) {
            const float wx = ((unsigned)xx < (unsigned)NX) ? 1.f : 0.f;
            wr = wx * wy[r]; wm = wr * wzm; we = wr * wze;
        }
        #pragma unroll
        for (int j = 0; j < 6; ++j) {
            if (SAFE) {
                float t = R.t[r][j], p = R.p[r][j];
                if (j == 0) { t *= wzm; p *= wzm; }
                if (j == 5) { t *= wze; p *= wze; }
                if (r == 0) { S[0][j]=t;  S[1][j]=p;  S[2][j]=t*t;          S[3][j]=p*p;          S[4][j]=t*p; }
                else        { S[0][j]+=t; S[1][j]+=p; S[2][j]=fmaf(t,t,S[2][j]); S[3][j]=fmaf(p,p,S[3][j]); S[4][j]=fmaf(t,p,S[4][j]); }
            } else {
                const float t = R.t[r][j], p = R.p[r][j];
                const float wj = (j == 0) ? wm : ((j == 5) ? we : wr);
                const float tw = t * wj, pw = p * wj;      // w in {0,1} => exact
                if (r == 0) { S[0][j]=tw;  S[1][j]=pw;  S[2][j]=tw*t;          S[3][j]=pw*p;          S[4][j]=tw*p; }
                else        { S[0][j]+=tw; S[1][j]+=pw; S[2][j]=fmaf(tw,t,S[2][j]); S[3][j]=fmaf(pw,p,S[3][j]); S[4][j]=fmaf(tw,p,S[4][j]); }
            }
        }
    }
    // 3-tap z-fold, 6 adds per quantity via pair reuse
    #pragma unroll
    for (int q = 0; q < 5; ++q) {
        const float m12 = S[q][1] + S[q][2];
        const float m34 = S[q][3] + S[q][4];
        W[q][0] = S[q][0] + m12;
        W[q][1] = m12 + S[q][3];
        W[q][2] = S[q][2] + m34;
        W[q][3] = m34 + S[q][5];
    }
}

__device__ __forceinline__ float epilogue4(const float P[5][ZPT], const float Wn[5][ZPT])
{
    constexpr float inv_vol = 1.0f / 27.0f;
    float acc = 0.f;
    #pragma unroll
    for (int zz = 0; zz < ZPT; ++zz) {
        const float st  = P[0][zz] + Wn[0][zz];
        const float sp  = P[1][zz] + Wn[1][zz];
        const float st2 = P[2][zz] + Wn[2][zz];
        const float sp2 = P[3][zz] + Wn[3][zz];
        const float stp = P[4][zz] + Wn[4][zz];
        const float tavg = st * inv_vol;
        const float pavg = sp * inv_vol;
        const float cross = fmaf(-pavg, st, stp);
        const float tvar  = fmaxf(fmaf(-tavg, st, st2), 0.f);
        const float pvar  = fmaxf(fmaf(-pavg, sp, sp2), 0.f);
        acc += cross * cross * __builtin_amdgcn_rcpf(fmaf(tvar, pvar, 1e-5f));
    }
    return acc;
}

template<bool SAFE>
__device__ __forceinline__ float march(const float* __restrict__ pred,
                                       const float* __restrict__ label,
                                       int xs0, const int rowoff[3], const float wy[3],
                                       int dm, int de, float wzm, float wze)
{
    Raw RA, RB;
    float U[5][ZPT], V[5][ZPT], P[5][ZPT];

    loadPlane<SAFE>(pred, label, xs0 - 1, rowoff, dm, de, RA);
    loadPlane<SAFE>(pred, label, xs0,     rowoff, dm, de, RB);
    __builtin_amdgcn_sched_barrier(0);
    foldPlane<SAFE>(RA, xs0 - 1, wy, wzm, wze, U);
    loadPlane<SAFE>(pred, label, xs0 + 1, rowoff, dm, de, RA);
    __builtin_amdgcn_sched_barrier(0);
    foldPlane<SAFE>(RB, xs0, wy, wzm, wze, V);
    #pragma unroll
    for (int q = 0; q < 5; ++q)
        #pragma unroll
        for (int zz = 0; zz < ZPT; ++zz)
            P[q][zz] = U[q][zz] + V[q][zz];

    float acc = 0.f;

    // step s: issue loads of plane xs0+s+2 into BUF_LD (pinned above the fold
    // by sched_barrier), fold plane xs0+s+1 from BUF_FD into WDST, emit output
    // at xs0+s, update P = WOTH + WDST.
#define NCC_STEP(S_, BUF_FD, BUF_LD, WDST, WOTH, DOLOAD)                        \
    do {                                                                        \
        if (DOLOAD) {                                                           \
            loadPlane<SAFE>(pred, label, xs0 + (S_) + 2, rowoff, dm, de, BUF_LD); \
            __builtin_amdgcn_sched_barrier(0);                                  \
        }                                                                       \
        foldPlane<SAFE>(BUF_FD, xs0 + (S_) + 1, wy, wzm, wze, WDST);            \
        acc += epilogue4(P, WDST);                                              \
        _Pragma("unroll")                                                       \
        for (int q = 0; q < 5; ++q)                                             \
            _Pragma("unroll")                                                   \
            for (int zz = 0; zz < ZPT; ++zz)                                    \
                P[q][zz] = WOTH[q][zz] + WDST[q][zz];                           \
    } while (0)

    NCC_STEP(0, RA, RB, U, V, true);
    NCC_STEP(1, RB, RA, V, U, true);
    NCC_STEP(2, RA, RB, U, V, true);
    NCC_STEP(3, RB, RA, V, U, true);
    NCC_STEP(4, RA, RB, U, V, true);
    NCC_STEP(5, RB, RA, V, U, true);
    NCC_STEP(6, RA, RB, U, V, true);
    NCC_STEP(7, RB, RA, V, U, false);
#undef NCC_STEP
    return acc;
}

__global__ __launch_bounds__(BLOCK_THREADS, 2)
void ncc_partial(const float* __restrict__ pred, const float* __restrict__ label,
                 float* __restrict__ partials)
{
    const int zc  = threadIdx.x;
    const int ty  = threadIdx.y;
    const int z0  = zc * ZPT;
    const int y   = blockIdx.x * BY + ty;
    const int xs0 = blockIdx.y * XSEG;
    const int b   = blockIdx.z;

    float wy[3];
    int   rowoff[3];
    #pragma unroll
    for (int r = 0; r < 3; ++r) {
        const int yy = y + r - 1;
        wy[r] = ((unsigned)yy < (unsigned)NY) ? 1.f : 0.f;
        const int yycl = min(max(yy, 0), NY - 1);
        rowoff[r] = b * (NX * PLANE) + yycl * NZ + z0;
    }
    const int   dm  = (zc == 0) ? 0 : 1;
    const int   de  = (zc == TZ - 1) ? 0 : ZPT;
    const float wzm = (zc == 0) ? 0.f : 1.f;
    const float wze = (zc == TZ - 1) ? 0.f : 1.f;

    // interior blocks (88%): every x-plane and y-row touched is in range
    const bool safe = (blockIdx.x >= 1) && (blockIdx.x <= NYB - 2) &&
                      (blockIdx.y >= 1) && (blockIdx.y <= NXB - 2);

    const float acc = safe
        ? march<true >(pred, label, xs0, rowoff, wy, dm, de, wzm, wze)
        : march<false>(pred, label, xs0, rowoff, wy, dm, de, wzm, wze);

    // wave (64) reduction, then block sum
    float a = acc;
    #pragma unroll
    for (int o = 32; o > 0; o >>= 1)
        a += __shfl_down(a, o, 64);

    __shared__ float wsum[BLOCK_THREADS / 64];
    const int tid = threadIdx.x + threadIdx.y * TZ;
    if ((tid & 63) == 0) wsum[tid >> 6] = a;
    __syncthreads();
    if (tid == 0) {
        float s = 0.f;
        #pragma unroll
        for (int w = 0; w < BLOCK_THREADS / 64; ++w) s += wsum[w];
        partials[blockIdx.x + (int)gridDim.x * (blockIdx.y + (int)gridDim.y * blockIdx.z)] = s;
    }
}

__global__ __launch_bounds__(256)
void ncc_reduce(const float* __restrict__ partials, int n, float* __restrict__ out)
{
    __shared__ double sh[256];
    double s = 0.0;
    for (int i = threadIdx.x; i < n; i += 256) s += (double)partials[i];
    sh[threadIdx.x] = s;
    __syncthreads();
    for (int off = 128; off > 0; off >>= 1) {
        if ((int)threadIdx.x < off) sh[threadIdx.x] += sh[threadIdx.x + off];
        __syncthreads();
    }
    if (threadIdx.x == 0) {
        const double nvox = (double)NB * NX * NY * NZ;
        out[0] = (float)(-sh[0] / nvox);
    }
}

extern "C" void kernel_launch(void* const* d_in, const int* in_sizes, int n_in,
                              void* d_out, int out_size, void* d_ws, size_t ws_size,
                              hipStream_t stream) {
    const float* pred  = (const float*)d_in[0];
    const float* label = (const float*)d_in[1];
    float* out = (float*)d_out;
    float* partials = (float*)d_ws;

    dim3 block(TZ, BY, 1);                 // 48 x 4 = 192 threads
    dim3 grid(NYB, NXB, NB);               // 48 x 24 x 2 = 2304 blocks

    ncc_partial<<<grid, block, 0, stream>>>(pred, label, partials);
    ncc_reduce<<<1, 256, 0, stream>>>(partials, NBLK, out);
}

// Round 5
// 134.151 us; speedup vs baseline: 3.4472x; 3.4472x over previous
//
#include <hip/hip_runtime.h>

constexpr int NX = 192, NY = 192, NZ = 192, NB = 2;
constexpr int ZPT  = 4;           // z outputs per thread
constexpr int TZ   = NZ / ZPT;    // 48
constexpr int BY   = 4;           // y rows per block
constexpr int XSEG = 4;           // x outputs per thread
constexpr int BLOCK_THREADS = TZ * BY;   // 192 = 3 waves
constexpr int PLANE = NY * NZ;
constexpr int NXB = NX / XSEG;    // 48
constexpr int NYB = NY / BY;      // 48
constexpr int NBLK = NYB * NXB * NB;     // 4608 blocks

struct Raw { float t[3][6]; float p[3][6]; };

template<bool SAFE>
__device__ __forceinline__ void loadPlane(const float* __restrict__ pred,
                                          const float* __restrict__ label,
                                          int xx, const int rowoff[3],
                                          int dm, int de, Raw& R)
{
    const int xcl  = SAFE ? xx : min(max(xx, 0), NX - 1);
    const int xoff = xcl * PLANE;
    #pragma unroll
    for (int r = 0; r < 3; ++r) {
        const int off = xoff + rowoff[r];
        const float4 t4 = *reinterpret_cast<const float4*>(label + off);
        const float4 p4 = *reinterpret_cast<const float4*>(pred + off);
        R.t[r][0] = label[off - dm];  R.p[r][0] = pred[off - dm];
        R.t[r][1] = t4.x; R.t[r][2] = t4.y; R.t[r][3] = t4.z; R.t[r][4] = t4.w;
        R.p[r][1] = p4.x; R.p[r][2] = p4.y; R.p[r][3] = p4.z; R.p[r][4] = p4.w;
        R.t[r][5] = label[off + de];  R.p[r][5] = pred[off + de];
    }
}

template<bool SAFE>
__device__ __forceinline__ void foldPlane(const Raw& R, int xx,
                                          const float wy[3], float wzm, float wze,
                                          float W[5][ZPT])
{
    float S[5][6];
    #pragma unroll
    for (int r = 0; r < 3; ++r) {
        float wr = 1.f, wm = 1.f, we = 1.f;
        if (!SAFE) {
            const float wx = ((unsigned)xx < (unsigned)NX) ? 1.f : 0.f;
            wr = wx * wy[r]; wm = wr * wzm; we = wr * wze;
        }
        #pragma unroll
        for (int j = 0; j < 6; ++j) {
            if (SAFE) {
                float t = R.t[r][j], p = R.p[r][j];
                if (j == 0) { t *= wzm; p *= wzm; }
                if (j == 5) { t *= wze; p *= wze; }
                if (r == 0) { S[0][j]=t;  S[1][j]=p;  S[2][j]=t*t;          S[3][j]=p*p;          S[4][j]=t*p; }
                else        { S[0][j]+=t; S[1][j]+=p; S[2][j]=fmaf(t,t,S[2][j]); S[3][j]=fmaf(p,p,S[3][j]); S[4][j]=fmaf(t,p,S[4][j]); }
            } else {
                const float t = R.t[r][j], p = R.p[r][j];
                const float wj = (j == 0) ? wm : ((j == 5) ? we : wr);
                const float tw = t * wj, pw = p * wj;      // w in {0,1} => exact
                if (r == 0) { S[0][j]=tw;  S[1][j]=pw;  S[2][j]=tw*t;          S[3][j]=pw*p;          S[4][j]=tw*p; }
                else        { S[0][j]+=tw; S[1][j]+=pw; S[2][j]=fmaf(tw,t,S[2][j]); S[3][j]=fmaf(pw,p,S[3][j]); S[4][j]=fmaf(tw,p,S[4][j]); }
            }
        }
    }
    // 3-tap z-fold, 6 adds per quantity via pair reuse
    #pragma unroll
    for (int q = 0; q < 5; ++q) {
        const float m12 = S[q][1] + S[q][2];
        const float m34 = S[q][3] + S[q][4];
        W[q][0] = S[q][0] + m12;
        W[q][1] = m12 + S[q][3];
        W[q][2] = S[q][2] + m34;
        W[q][3] = m34 + S[q][5];
    }
}

__device__ __forceinline__ float epilogue4(const float P[5][ZPT], const float Wn[5][ZPT])
{
    constexpr float inv_vol = 1.0f / 27.0f;
    float acc = 0.f;
    #pragma unroll
    for (int zz = 0; zz < ZPT; ++zz) {
        const float st  = P[0][zz] + Wn[0][zz];
        const float sp  = P[1][zz] + Wn[1][zz];
        const float st2 = P[2][zz] + Wn[2][zz];
        const float sp2 = P[3][zz] + Wn[3][zz];
        const float stp = P[4][zz] + Wn[4][zz];
        const float tavg = st * inv_vol;
        const float pavg = sp * inv_vol;
        const float cross = fmaf(-pavg, st, stp);
        const float tvar  = fmaxf(fmaf(-tavg, st, st2), 0.f);
        const float pvar  = fmaxf(fmaf(-pavg, sp, sp2), 0.f);
        acc += cross * cross * __builtin_amdgcn_rcpf(fmaf(tvar, pvar, 1e-5f));
    }
    return acc;
}

template<bool SAFE>
__device__ __forceinline__ float march(const float* __restrict__ pred,
                                       const float* __restrict__ label,
                                       int xs0, const int rowoff[3], const float wy[3],
                                       int dm, int de, float wzm, float wze)
{
    Raw RA, RB;
    float U[5][ZPT], V[5][ZPT], P[5][ZPT];

    loadPlane<SAFE>(pred, label, xs0 - 1, rowoff, dm, de, RA);
    loadPlane<SAFE>(pred, label, xs0,     rowoff, dm, de, RB);
    foldPlane<SAFE>(RA, xs0 - 1, wy, wzm, wze, U);
    loadPlane<SAFE>(pred, label, xs0 + 1, rowoff, dm, de, RA);
    foldPlane<SAFE>(RB, xs0, wy, wzm, wze, V);
    #pragma unroll
    for (int q = 0; q < 5; ++q)
        #pragma unroll
        for (int zz = 0; zz < ZPT; ++zz)
            P[q][zz] = U[q][zz] + V[q][zz];

    float acc = 0.f;

    // step s: issue loads of plane xs0+s+2 into BUF_LD, fold plane xs0+s+1
    // from BUF_FD into WDST, emit output at xs0+s, update P = WOTH + WDST.
#define NCC_STEP(S_, BUF_FD, BUF_LD, WDST, WOTH, DOLOAD)                        \
    do {                                                                        \
        if (DOLOAD)                                                             \
            loadPlane<SAFE>(pred, label, xs0 + (S_) + 2, rowoff, dm, de, BUF_LD); \
        foldPlane<SAFE>(BUF_FD, xs0 + (S_) + 1, wy, wzm, wze, WDST);            \
        acc += epilogue4(P, WDST);                                              \
        _Pragma("unroll")                                                       \
        for (int q = 0; q < 5; ++q)                                             \
            _Pragma("unroll")                                                   \
            for (int zz = 0; zz < ZPT; ++zz)                                    \
                P[q][zz] = WOTH[q][zz] + WDST[q][zz];                           \
    } while (0)

    NCC_STEP(0, RA, RB, U, V, true);
    NCC_STEP(1, RB, RA, V, U, true);
    NCC_STEP(2, RA, RB, U, V, true);
    NCC_STEP(3, RB, RA, V, U, false);
#undef NCC_STEP
    return acc;
}

__global__ __launch_bounds__(BLOCK_THREADS)
void ncc_partial(const float* __restrict__ pred, const float* __restrict__ label,
                 float* __restrict__ partials)
{
    const int zc  = threadIdx.x;
    const int ty  = threadIdx.y;
    const int z0  = zc * ZPT;
    const int y   = blockIdx.x * BY + ty;
    const int xs0 = blockIdx.y * XSEG;
    const int b   = blockIdx.z;

    float wy[3];
    int   rowoff[3];
    #pragma unroll
    for (int r = 0; r < 3; ++r) {
        const int yy = y + r - 1;
        wy[r] = ((unsigned)yy < (unsigned)NY) ? 1.f : 0.f;
        const int yycl = min(max(yy, 0), NY - 1);
        rowoff[r] = b * (NX * PLANE) + yycl * NZ + z0;
    }
    const int   dm  = (zc == 0) ? 0 : 1;
    const int   de  = (zc == TZ - 1) ? 0 : ZPT;
    const float wzm = (zc == 0) ? 0.f : 1.f;
    const float wze = (zc == TZ - 1) ? 0.f : 1.f;

    // interior blocks: every x-plane and y-row touched is in range
    const bool safe = (blockIdx.x >= 1) && (blockIdx.x <= NYB - 2) &&
                      (blockIdx.y >= 1) && (blockIdx.y <= NXB - 2);

    const float acc = safe
        ? march<true >(pred, label, xs0, rowoff, wy, dm, de, wzm, wze)
        : march<false>(pred, label, xs0, rowoff, wy, dm, de, wzm, wze);

    // wave (64) reduction, then block sum
    float a = acc;
    #pragma unroll
    for (int o = 32; o > 0; o >>= 1)
        a += __shfl_down(a, o, 64);

    __shared__ float wsum[BLOCK_THREADS / 64];
    const int tid = threadIdx.x + threadIdx.y * TZ;
    if ((tid & 63) == 0) wsum[tid >> 6] = a;
    __syncthreads();
    if (tid == 0) {
        float s = 0.f;
        #pragma unroll
        for (int w = 0; w < BLOCK_THREADS / 64; ++w) s += wsum[w];
        partials[blockIdx.x + (int)gridDim.x * (blockIdx.y + (int)gridDim.y * blockIdx.z)] = s;
    }
}

__global__ __launch_bounds__(256)
void ncc_reduce(const float* __restrict__ partials, int n, float* __restrict__ out)
{
    __shared__ double sh[256];
    double s = 0.0;
    for (int i = threadIdx.x; i < n; i += 256) s += (double)partials[i];
    sh[threadIdx.x] = s;
    __syncthreads();
    for (int off = 128; off > 0; off >>= 1) {
        if ((int)threadIdx.x < off) sh[threadIdx.x] += sh[threadIdx.x + off];
        __syncthreads();
    }
    if (threadIdx.x == 0) {
        const double nvox = (double)NB * NX * NY * NZ;
        out[0] = (float)(-sh[0] / nvox);
    }
}

extern "C" void kernel_launch(void* const* d_in, const int* in_sizes, int n_in,
                              void* d_out, int out_size, void* d_ws, size_t ws_size,
                              hipStream_t stream) {
    const float* pred  = (const float*)d_in[0];
    const float* label = (const float*)d_in[1];
    float* out = (float*)d_out;
    float* partials = (float*)d_ws;

    dim3 block(TZ, BY, 1);                 // 48 x 4 = 192 threads
    dim3 grid(NYB, NXB, NB);               // 48 x 48 x 2 = 4608 blocks

    ncc_partial<<<grid, block, 0, stream>>>(pred, label, partials);
    ncc_reduce<<<1, 256, 0, stream>>>(partials, NBLK, out);
}